// Round 15
// baseline (521.641 us; speedup 1.0000x reference)
//
#include <hip/hip_runtime.h>
#include <math.h>

// Shapes: B=2, T=2048, D=1024, H=8, S=32, Dh=128, 3D=3072, B*T=4096
// POLISH R30: base = R14/R29 (453.8us PASS). Single change: merge gemm_out
// (128x64 tiles, proven −5us in R29) into attn_write's grid as blocks 0..511;
// attn_write becomes blocks 512..16895. Removes the serialized ~11us gemm_out
// dispatch — its MFMA/LDS K-loops now overlap attn_write's store-bound flood
// (disjoint pipes). LDS union 24KB caps attn_write at 6 blocks/CU (was 8);
// R4's "low occupancy kills attn_write" data was confounded by its 1.55x
// write-amplified stores, so 24 waves/CU should still saturate the store path.
// R8's earlier merge failed on 64^2 tile traffic, NOT on the merge concept.

typedef __attribute__((ext_vector_type(8))) short s16x8;
typedef __attribute__((ext_vector_type(4))) short s16x4;
typedef __attribute__((ext_vector_type(4))) float f32x4;

__device__ inline short f2bf(float f) {
  union { float f; unsigned u; } v; v.f = f;
  unsigned r = v.u + 0x7FFFu + ((v.u >> 16) & 1u);
  return (short)(r >> 16);
}
__device__ inline float bf2f(short s) {
  union { unsigned u; float f; } v;
  v.u = ((unsigned)(unsigned short)s) << 16;
  return v.f;
}
// Packed f32x2 -> bf16x2, RNE (identical rounding to f2bf).
__device__ inline unsigned cvt_pk_bf16(float lo, float hi) {
  unsigned r;
  asm("v_cvt_pk_bf16_f32 %0, %1, %2" : "=v"(r) : "v"(lo), "v"(hi));
  return r;
}
#define MFMA_BF16(a, b, c) __builtin_amdgcn_mfma_f32_16x16x32_bf16((a), (b), (c), 0, 0, 0)

// Async global->LDS, 16B per lane. LDS dest is wave-uniform base + lane*16.
#define GLOAD_LDS16(gsrc, ldst)                                          \
  __builtin_amdgcn_global_load_lds(                                      \
      (const __attribute__((address_space(1))) void*)(gsrc),             \
      (__attribute__((address_space(3))) void*)(ldst), 16, 0, 0)

// ---------------------------------------------------------------------------
// Fused prep (round-8 exact).
// ---------------------------------------------------------------------------
__device__ inline void transpose_tile32(const float* __restrict__ W,
                                        short* __restrict__ Wt, int K, int N,
                                        int n0, int k0) {
  __shared__ float tile[32][33];
  const int r = threadIdx.x >> 3, c4 = (threadIdx.x & 7) * 4;
  float4 v = *(const float4*)(W + (size_t)(k0 + r) * N + n0 + c4);
  tile[r][c4 + 0] = v.x; tile[r][c4 + 1] = v.y;
  tile[r][c4 + 2] = v.z; tile[r][c4 + 3] = v.w;
  __syncthreads();
  s16x4 o;
  o[0] = f2bf(tile[c4 + 0][r]);
  o[1] = f2bf(tile[c4 + 1][r]);
  o[2] = f2bf(tile[c4 + 2][r]);
  o[3] = f2bf(tile[c4 + 3][r]);
  *(s16x4*)(Wt + (size_t)(n0 + r) * K + k0 + c4) = o;
}

__global__ __launch_bounds__(256) void prep_fused(
    const float* __restrict__ x, short* __restrict__ x16,
    const float* __restrict__ Wqkv, short* __restrict__ Wqt16,
    const float* __restrict__ Wout, short* __restrict__ Wot16,
    const float* __restrict__ ctr, const float* __restrict__ ls,
    const float* __restrict__ la, short* __restrict__ c16,
    float* __restrict__ csq, float* __restrict__ inv2, float* __restrict__ amp) {
  const int bx = blockIdx.x;
  if (bx < 4096) {
    int i = bx * 256 + threadIdx.x;
    float4 v = ((const float4*)x)[i];
    s16x4 o;
    o[0] = f2bf(v.x); o[1] = f2bf(v.y); o[2] = f2bf(v.z); o[3] = f2bf(v.w);
    ((s16x4*)x16)[i] = o;
  } else if (bx < 7168) {
    int idx = bx - 4096;
    transpose_tile32(Wqkv, Wqt16, 1024, 3072, (idx % 96) * 32, (idx / 96) * 32);
  } else if (bx < 8192) {
    int idx = bx - 7168;
    transpose_tile32(Wout, Wot16, 1024, 1024, (idx % 32) * 32, (idx / 32) * 32);
  } else {
    const int t = threadIdx.x;
    float sumsq = 0.f;
#pragma unroll
    for (int d = 0; d < 128; d += 4) {
      float4 v = *(const float4*)(ctr + (size_t)t * 128 + d);
      sumsq += v.x * v.x + v.y * v.y + v.z * v.z + v.w * v.w;
      s16x4 o;
      o[0] = f2bf(v.x); o[1] = f2bf(v.y); o[2] = f2bf(v.z); o[3] = f2bf(v.w);
      *(s16x4*)(c16 + (size_t)t * 128 + d) = o;
    }
    csq[t] = sumsq;
    float sc = __expf(ls[t]);
    float iv = 1.0f / (sc + 1e-6f);
    inv2[t] = -0.5f * iv * iv;
    amp[t] = __expf(la[t]);
  }
}

// ---------------------------------------------------------------------------
// bf16 MFMA GEMM, m97-style LDS staging — QKV (R12 exact).
// q/k: direct row-major bf16 stores. v: LDS-transposed coalesced s16x8 rows.
// ---------------------------------------------------------------------------
template <int N, bool SCATTER>
__global__ __launch_bounds__(256) void gemm_bf16(
    const short* __restrict__ A, const short* __restrict__ Wt,
    const float* __restrict__ bias,
    short* __restrict__ q16, short* __restrict__ k16, short* __restrict__ vt16,
    float* __restrict__ outf) {
  __shared__ union {
    struct { short As[128 * 64]; short Bs[128 * 64]; } s;  // 32 KB
    short tv[128 * 136];                                   // 34 KB (v-transpose)
  } sm;
  const int tid = threadIdx.x;
  const int w = tid >> 6, l = tid & 63;
  const int lm = l & 15, lk = l >> 4;
  const int bn0 = blockIdx.x * 128;
  const int bm0 = blockIdx.y * 128;
  const int n0 = bn0 + (w & 1) * 64;
  const int m0 = bm0 + (w >> 1) * 64;
  const int K = 1024;
  f32x4 acc[4][4];
#pragma unroll
  for (int mi = 0; mi < 4; mi++)
#pragma unroll
    for (int ni = 0; ni < 4; ni++) acc[mi][ni] = (f32x4){0.f, 0.f, 0.f, 0.f};

  const int srow = l >> 3;
  const int scol = (l & 7) * 8;
  const int mh = (w >> 1) * 64, nh = (w & 1) * 64;

  for (int k0 = 0; k0 < K; k0 += 64) {
#pragma unroll
    for (int q = 0; q < 4; q++) {
      const int chunk = w * 4 + q;
      const int row = chunk * 8 + srow;
      GLOAD_LDS16(A + (size_t)(bm0 + row) * K + k0 + scol, sm.s.As + chunk * 512);
      GLOAD_LDS16(Wt + (size_t)(bn0 + row) * K + k0 + scol, sm.s.Bs + chunk * 512);
    }
    __syncthreads();
#pragma unroll
    for (int kk = 0; kk < 2; kk++) {
      s16x8 af[4], bf[4];
#pragma unroll
      for (int i = 0; i < 4; i++) {
        af[i] = *(const s16x8*)(sm.s.As + (mh + i * 16 + lm) * 64 + kk * 32 + lk * 8);
        bf[i] = *(const s16x8*)(sm.s.Bs + (nh + i * 16 + lm) * 64 + kk * 32 + lk * 8);
      }
#pragma unroll
      for (int mi = 0; mi < 4; mi++)
#pragma unroll
        for (int ni = 0; ni < 4; ni++)
          acc[mi][ni] = MFMA_BF16(af[mi], bf[ni], acc[mi][ni]);
    }
    __syncthreads();
  }
  if (SCATTER) {
    const int three = bn0 >> 10;
    if (three < 2) {
      // q/k: direct row-major bf16 stores (R10 path, proven).
      short* dst0 = three ? k16 : q16;
      const int h = (bn0 >> 7) & 7;
      const int bb = bm0 >> 11;
      const int bh = bb * 8 + h;
      const int tt0 = bm0 & 2047;
#pragma unroll
      for (int ni = 0; ni < 4; ni++) {
        const int n = n0 + ni * 16 + lm;
        const int dh = n & 127;
        const float bv = bias[n];
#pragma unroll
        for (int mi = 0; mi < 4; mi++) {
#pragma unroll
          for (int r = 0; r < 4; r++) {
            const int ml = mh + mi * 16 + lk * 4 + r;
            dst0[((size_t)bh * 2048 + tt0 + ml) * 128 + dh] =
                f2bf(acc[mi][ni][r] + bv);
          }
        }
      }
    } else {
      // v: stage n-major in LDS, then coalesced transposed write-out.
      const int h = (bn0 >> 7) & 7;
      const int bb = bm0 >> 11;
      const int bh = bb * 8 + h;
      const int tt0 = bm0 & 2047;
#pragma unroll
      for (int ni = 0; ni < 4; ni++) {
        const int nl = nh + ni * 16 + lm;
        const float bv = bias[bn0 + nl];
#pragma unroll
        for (int mi = 0; mi < 4; mi++) {
          const int ml = mh + mi * 16 + lk * 4;
          s16x4 o;
          o[0] = f2bf(acc[mi][ni][0] + bv);
          o[1] = f2bf(acc[mi][ni][1] + bv);
          o[2] = f2bf(acc[mi][ni][2] + bv);
          o[3] = f2bf(acc[mi][ni][3] + bv);
          *(s16x4*)(sm.tv + nl * 136 + ml) = o;
        }
      }
      __syncthreads();
#pragma unroll
      for (int c = 0; c < 8; c++) {
        const int u = c * 256 + tid;
        const int n = u >> 4, ch = u & 15;
        s16x8 vv = *(const s16x8*)(sm.tv + n * 136 + ch * 8);
        *(s16x8*)(vt16 + ((size_t)(bh * 128 + n)) * 2048 + tt0 + ch * 8) = vv;
      }
    }
  } else {
#pragma unroll
    for (int ni = 0; ni < 4; ni++) {
      const int n = n0 + ni * 16 + lm;
      const float bv = bias[n];
#pragma unroll
      for (int mi = 0; mi < 4; mi++) {
#pragma unroll
        for (int r = 0; r < 4; r++) {
          const int m = m0 + mi * 16 + lk * 4 + r;
          outf[(size_t)m * N + n] = acc[mi][ni][r] + bv;
        }
      }
    }
  }
}

// ---------------------------------------------------------------------------
// splat: q/k weights via MFMA against centers (1024 blocks) — R12 exact.
// ---------------------------------------------------------------------------
__global__ __launch_bounds__(256) void splat_tv(
    const short* __restrict__ q16, const short* __restrict__ k16,
    const short* __restrict__ c16, const float* __restrict__ csq,
    const float* __restrict__ inv2, const float* __restrict__ amp,
    short* __restrict__ qa16, short* __restrict__ kw16) {
  const int tid = threadIdx.x;
  const int it = blockIdx.x & 31;
  const int bh = (blockIdx.x >> 5) & 15;
  const int which = blockIdx.x >> 9;
  const int w = tid >> 6, l = tid & 63;
  const int lm = l & 15, lk = l >> 4;
  const int h = bh & 7;
  const int i0 = it * 64 + w * 16;
  const short* src = which ? k16 : q16;

  s16x8 af[4];
  float sq = 0.f;
#pragma unroll
  for (int kk = 0; kk < 4; kk++) {
    af[kk] = *(const s16x8*)(src + ((size_t)bh * 2048 + i0 + lm) * 128 + kk * 32 + lk * 8);
#pragma unroll
    for (int j = 0; j < 8; j++) {
      float f = bf2f(af[kk][j]);
      sq += f * f;
    }
  }
  sq += __shfl_xor(sq, 16);
  sq += __shfl_xor(sq, 32);

  f32x4 acc[2];
  acc[0] = (f32x4){0.f, 0.f, 0.f, 0.f};
  acc[1] = (f32x4){0.f, 0.f, 0.f, 0.f};
#pragma unroll
  for (int kk = 0; kk < 4; kk++) {
    s16x8 b0 = *(const s16x8*)(c16 + (size_t)(h * 32 + lm) * 128 + kk * 32 + lk * 8);
    s16x8 b1 = *(const s16x8*)(c16 + (size_t)(h * 32 + 16 + lm) * 128 + kk * 32 + lk * 8);
    acc[0] = MFMA_BF16(af[kk], b0, acc[0]);
    acc[1] = MFMA_BF16(af[kk], b1, acc[1]);
  }
  short* dst = which ? kw16 : qa16;
#pragma unroll
  for (int ni = 0; ni < 2; ni++) {
    const int n = ni * 16 + lm;
    const float cs = csq[h * 32 + n];
    const float iv2 = inv2[h * 32 + n];
    const float am = which ? 1.0f : amp[h * 32 + n];
#pragma unroll
    for (int r = 0; r < 4; r++) {
      float qs = __shfl(sq, lk * 4 + r);
      float d2 = fmaxf(qs + cs - 2.0f * acc[ni][r], 0.0f);
      float wv = __expf(iv2 * d2) * am;
      int m = i0 + lk * 4 + r;
      dst[((size_t)bh * 2048 + m) * 32 + n] = f2bf(wv);
    }
  }
}

// ---------------------------------------------------------------------------
// Flash attention v11 (R12 exact): sigma-relabeled swapped-QK + LDS-staged V
// dbuf, full j-range, fused normalize -> direct aout16/lrow write.
// ---------------------------------------------------------------------------
__global__ __launch_bounds__(256) void attn_flash(
    const short* __restrict__ qa16, const short* __restrict__ kw16,
    const short* __restrict__ vt16, const float* __restrict__ temp,
    float* __restrict__ lrow, short* __restrict__ aout16) {
  __shared__ short Vs[2][8192];  // 2 x 16KB: [128 rows][8 slots of 16B]
  const int tid = threadIdx.x;
  const int w = tid >> 6, l = tid & 63;
  const int lm = l & 15, lk = l >> 4;
  const int it = blockIdx.x, h = blockIdx.y;
  const int b = blockIdx.z;
  const int bh = b * 8 + h;
  const int i0 = it * 64 + w * 16;
  const float invT = 1.0f / temp[0];
  const short* kwb = kw16 + (size_t)bh * 2048 * 32;
  const short* vtb = vt16 + (size_t)bh * 128 * 2048;
  s16x8 qfrag = *(const s16x8*)(qa16 + ((size_t)(bh * 2048 + i0 + lm)) * 32 + lk * 8);
  float lsum = 0.f;
  f32x4 acc[8];
#pragma unroll
  for (int d = 0; d < 8; d++) acc[d] = (f32x4){0.f, 0.f, 0.f, 0.f};

  const int sig0 = (lm >> 2) * 8 + (lm & 3);
  const int srow8 = l >> 3;
  const int scb = (l & 7) ^ srow8;
  const int rcb0 = (lk ^ (lm & 7)) * 8;
  const int rcb1 = ((lk + 4) ^ (lm & 7)) * 8;

#pragma unroll
  for (int q = 0; q < 4; q++) {
    const int chunk = w * 4 + q;
    GLOAD_LDS16(vtb + (size_t)(chunk * 8 + srow8) * 2048 + scb * 8,
                &Vs[0][chunk * 512]);
  }
  __syncthreads();

  int cur = 0;
  for (int jc = 0; jc < 2048; jc += 64) {
    if (jc + 64 < 2048) {
#pragma unroll
      for (int q = 0; q < 4; q++) {
        const int chunk = w * 4 + q;
        GLOAD_LDS16(vtb + (size_t)(chunk * 8 + srow8) * 2048 + (jc + 64) + scb * 8,
                    &Vs[cur ^ 1][chunk * 512]);
      }
    }
    s16x8 kb[4];
    kb[0] = *(const s16x8*)(kwb + (size_t)(jc + sig0) * 32 + lk * 8);
    kb[1] = *(const s16x8*)(kwb + (size_t)(jc + sig0 + 4) * 32 + lk * 8);
    kb[2] = *(const s16x8*)(kwb + (size_t)(jc + sig0 + 32) * 32 + lk * 8);
    kb[3] = *(const s16x8*)(kwb + (size_t)(jc + sig0 + 36) * 32 + lk * 8);
    f32x4 z = (f32x4){0.f, 0.f, 0.f, 0.f};
    f32x4 s[4];
#pragma unroll
    for (int c = 0; c < 4; c++) s[c] = MFMA_BF16(kb[c], qfrag, z);
    float p[4][4];
#pragma unroll
    for (int c = 0; c < 4; c++) {
      p[c][0] = __expf(s[c][0] * invT);
      p[c][1] = __expf(s[c][1] * invT);
      p[c][2] = __expf(s[c][2] * invT);
      p[c][3] = __expf(s[c][3] * invT);
      lsum += (p[c][0] + p[c][1]) + (p[c][2] + p[c][3]);
    }
    union { unsigned u[4]; s16x8 v; } t0, t1;
    t0.u[0] = cvt_pk_bf16(p[0][0], p[0][1]);
    t0.u[1] = cvt_pk_bf16(p[0][2], p[0][3]);
    t0.u[2] = cvt_pk_bf16(p[1][0], p[1][1]);
    t0.u[3] = cvt_pk_bf16(p[1][2], p[1][3]);
    t1.u[0] = cvt_pk_bf16(p[2][0], p[2][1]);
    t1.u[1] = cvt_pk_bf16(p[2][2], p[2][3]);
    t1.u[2] = cvt_pk_bf16(p[3][0], p[3][1]);
    t1.u[3] = cvt_pk_bf16(p[3][2], p[3][3]);
    s16x8 pf0 = t0.v, pf1 = t1.v;
    const short* vb = Vs[cur];
#pragma unroll
    for (int d = 0; d < 8; d++) {
      const short* vsrow = vb + (d * 16 + lm) * 64;
      s16x8 vb0 = *(const s16x8*)(vsrow + rcb0);
      s16x8 vb1 = *(const s16x8*)(vsrow + rcb1);
      acc[d] = MFMA_BF16(pf0, vb0, acc[d]);
      acc[d] = MFMA_BF16(pf1, vb1, acc[d]);
    }
    __syncthreads();
    cur ^= 1;
  }
  lsum += __shfl_xor(lsum, 16);
  lsum += __shfl_xor(lsum, 32);
  if (l < 16) lrow[bh * 2048 + i0 + l] = lsum;
  float invl[4];
#pragma unroll
  for (int r = 0; r < 4; r++) invl[r] = 1.0f / __shfl(lsum, lk * 4 + r);
  short* ob = aout16 + ((size_t)(b * 2048 + i0)) * 1024 + h * 128 + lm;
#pragma unroll
  for (int r = 0; r < 4; r++) {
    const int row = lk * 4 + r;
#pragma unroll
    for (int d = 0; d < 8; d++)
      ob[(size_t)row * 1024 + d * 16] = f2bf(acc[d][r] * invl[r]);
  }
}

// ---------------------------------------------------------------------------
// Merged: gemm_out 128x64 (blocks 0..511, R29-proven) + attn_write
// (blocks 512..16895, R12-proven). LDS union 24KB.
// ---------------------------------------------------------------------------
__global__ __launch_bounds__(256) void attnw_gemmo(
    const short* __restrict__ qa16, const short* __restrict__ kw16,
    const float* __restrict__ lrow, const float* __restrict__ temp,
    float* __restrict__ attn,
    const short* __restrict__ aout16, const short* __restrict__ Wot16,
    const float* __restrict__ bout, float* __restrict__ out) {
  __shared__ union {
    struct { short As[128 * 64]; short Bs[64 * 64]; } g;  // 24 KB
    float pl[8][16][33];                                  // 16.9 KB
  } sm;
  const int tid = threadIdx.x;
  const int w = tid >> 6, l = tid & 63;
  const int lm = l & 15, lk = l >> 4;
  if (blockIdx.x < 512) {
    // ---- gemm_out 128(M)x64(N), R29 verbatim ----
    const int idx = blockIdx.x;
    const int bn0 = (idx & 15) * 64;
    const int bm0 = (idx >> 4) * 128;
    const int K = 1024;
    f32x4 acc[4][2];
#pragma unroll
    for (int mi = 0; mi < 4; mi++)
#pragma unroll
      for (int ni = 0; ni < 2; ni++) acc[mi][ni] = (f32x4){0.f, 0.f, 0.f, 0.f};
    const int srow = l >> 3;
    const int scol = (l & 7) * 8;
    const int mh = (w >> 1) * 64, nh = (w & 1) * 32;
    for (int k0 = 0; k0 < K; k0 += 64) {
#pragma unroll
      for (int q = 0; q < 4; q++) {
        const int chunk = w * 4 + q;                 // 0..15: 128 A-rows
        GLOAD_LDS16(aout16 + (size_t)(bm0 + chunk * 8 + srow) * K + k0 + scol,
                    sm.g.As + chunk * 512);
      }
#pragma unroll
      for (int q = 0; q < 2; q++) {
        const int chunk = w * 2 + q;                 // 0..7: 64 B-rows
        GLOAD_LDS16(Wot16 + (size_t)(bn0 + chunk * 8 + srow) * K + k0 + scol,
                    sm.g.Bs + chunk * 512);
      }
      __syncthreads();
#pragma unroll
      for (int kk = 0; kk < 2; kk++) {
        s16x8 af[4], bf[2];
#pragma unroll
        for (int i = 0; i < 4; i++)
          af[i] = *(const s16x8*)(sm.g.As + (mh + i * 16 + lm) * 64 + kk * 32 + lk * 8);
#pragma unroll
        for (int i = 0; i < 2; i++)
          bf[i] = *(const s16x8*)(sm.g.Bs + (nh + i * 16 + lm) * 64 + kk * 32 + lk * 8);
#pragma unroll
        for (int mi = 0; mi < 4; mi++)
#pragma unroll
          for (int ni = 0; ni < 2; ni++)
            acc[mi][ni] = MFMA_BF16(af[mi], bf[ni], acc[mi][ni]);
      }
      __syncthreads();
    }
#pragma unroll
    for (int ni = 0; ni < 2; ni++) {
      const int n = bn0 + nh + ni * 16 + lm;
      const float bv = bout[n];
#pragma unroll
      for (int mi = 0; mi < 4; mi++) {
#pragma unroll
        for (int r = 0; r < 4; r++) {
          const int m = bm0 + mh + mi * 16 + lk * 4 + r;
          out[(size_t)m * 1024 + n] = acc[mi][ni][r] + bv;
        }
      }
    }
  } else {
    // ---- attn_write 16x32 (R12 verbatim, bx shifted) ----
    const int bx = blockIdx.x - 512;
    const int i0 = (bx & 127) * 16;
    const int j0 = ((bx >> 7) & 63) * 32;
    const int b = bx >> 13;
    const float invT = 1.0f / temp[0];
#pragma unroll
    for (int hh = 0; hh < 2; hh++) {
      const int h = w * 2 + hh;
      const int bh = b * 8 + h;
      s16x8 qf = *(const s16x8*)(qa16 + ((size_t)(bh * 2048 + i0 + lm)) * 32 + lk * 8);
      s16x8 kf[2];
#pragma unroll
      for (int jh = 0; jh < 2; jh++)
        kf[jh] = *(const s16x8*)(kw16 + ((size_t)(bh * 2048 + j0 + jh * 16 + lm)) * 32 + lk * 8);
      float il[4];
#pragma unroll
      for (int r = 0; r < 4; r++)
        il[r] = 1.0f / lrow[bh * 2048 + i0 + lk * 4 + r];
      f32x4 z = (f32x4){0.f, 0.f, 0.f, 0.f};
#pragma unroll
      for (int jh = 0; jh < 2; jh++) {
        f32x4 s = MFMA_BF16(qf, kf[jh], z);
#pragma unroll
        for (int r = 0; r < 4; r++) {
          float p = __expf(s[r] * invT) * il[r];
          sm.pl[h][lk * 4 + r][jh * 16 + lm] = p;
        }
      }
    }
    __syncthreads();
#pragma unroll
    for (int c = 0; c < 4; c++) {
      int u = c * 256 + tid;
      int i = u >> 6, rem = u & 63;
      int j = rem >> 1, h4 = (rem & 1) * 4;
      f32x4 v;
      v[0] = sm.pl[h4][i][j];
      v[1] = sm.pl[h4 + 1][i][j];
      v[2] = sm.pl[h4 + 2][i][j];
      v[3] = sm.pl[h4 + 3][i][j];
      f32x4* dst = (f32x4*)(attn + (((size_t)(b * 2048 + i0 + i)) * 2048 + j0 + j) * 8 + h4);
      __builtin_nontemporal_store(v, dst);
    }
  }
}

// ---------------------------------------------------------------------------
extern "C" void kernel_launch(void* const* d_in, const int* in_sizes, int n_in,
                              void* d_out, int out_size, void* d_ws, size_t ws_size,
                              hipStream_t stream) {
  const float* x    = (const float*)d_in[0];
  const float* Wqkv = (const float*)d_in[1];
  const float* bqkv = (const float*)d_in[2];
  const float* Wout = (const float*)d_in[3];
  const float* bout = (const float*)d_in[4];
  const float* ctr  = (const float*)d_in[5];
  const float* ls   = (const float*)d_in[6];
  const float* la   = (const float*)d_in[7];
  const float* temp = (const float*)d_in[8];

  float* out = (float*)d_out;                 // (B,T,D)
  float* attn = out + 4194304;                // (B,T,T,H)

  short* ws16 = (short*)d_ws;
  short* q16   = ws16;                        // 4,194,304 sh (B,H,T,Dh) bf16
  short* k16   = q16 + 4194304;               // 4,194,304 sh
  short* vt16  = k16 + 4194304;               // 4,194,304 sh (B,H,Dh,T) bf16
  short* x16   = vt16 + 4194304;              // 4,194,304 sh
  short* Wqt16 = x16 + 4194304;               // 3,145,728 sh
  short* Wot16 = Wqt16 + 3145728;             // 1,048,576 sh
  short* qa16  = Wot16 + 1048576;             // 1,048,576 sh
  short* kw16  = qa16 + 1048576;              // 1,048,576 sh
  short* aout16 = kw16 + 1048576;             // 4,194,304 sh
  short* c16   = aout16 + 4194304;            // 32,768 sh
  float* lrow  = (float*)(c16 + 32768);       // 32,768 fl
  float* csq   = lrow + 32768;                // 256
  float* inv2  = csq + 256;
  float* amp   = inv2 + 256;

  prep_fused<<<8193, 256, 0, stream>>>(x, x16, Wqkv, Wqt16, Wout, Wot16,
                                       ctr, ls, la, c16, csq, inv2, amp);
  gemm_bf16<3072, true><<<dim3(24, 32), 256, 0, stream>>>(
      x16, Wqt16, bqkv, q16, k16, vt16, nullptr);
  splat_tv<<<1024, 256, 0, stream>>>(
      q16, k16, c16, csq, inv2, amp, qa16, kw16);
  attn_flash<<<dim3(32, 8, 2), 256, 0, stream>>>(
      qa16, kw16, vt16, temp, lrow, aout16);
  attnw_gemmo<<<16896, 256, 0, stream>>>(
      qa16, kw16, lrow, temp, attn, aout16, Wot16, bout, out);
}

// Round 16
// 448.683 us; speedup vs baseline: 1.1626x; 1.1626x over previous
//
#include <hip/hip_runtime.h>
#include <math.h>

// Shapes: B=2, T=2048, D=1024, H=8, S=32, Dh=128, 3D=3072, B*T=4096
// POLISH R31: base = R14 (453.8us PASS). R15's grid-merge regressed (+68us,
// LDS-union occupancy loss on attn_write — 2nd failed merge, concept dead).
// This round: FUSE SPLAT INTO THE QKV GEMM EPILOGUE. A q/k-third block
// computes 128 t-rows x all 128 dh of one (b,h) — exactly what splat needs.
// Epilogue stages f2bf(acc+bias) m-major into the 34KB tv union, syncs, then
// each wave runs the proven splat math (af from LDS ds_read_b128, layout
// identical to the old global A-frag; sq/MFMA/exp/store verbatim) on 32 rows.
// Deletes: splat_tv kernel (~25us serialized), q16/k16 buffers, 32MB traffic.
// v-third epilogue (LDS-transpose) and all other kernels R14-exact.

typedef __attribute__((ext_vector_type(8))) short s16x8;
typedef __attribute__((ext_vector_type(4))) short s16x4;
typedef __attribute__((ext_vector_type(4))) float f32x4;

__device__ inline short f2bf(float f) {
  union { float f; unsigned u; } v; v.f = f;
  unsigned r = v.u + 0x7FFFu + ((v.u >> 16) & 1u);
  return (short)(r >> 16);
}
__device__ inline float bf2f(short s) {
  union { unsigned u; float f; } v;
  v.u = ((unsigned)(unsigned short)s) << 16;
  return v.f;
}
// Packed f32x2 -> bf16x2, RNE (identical rounding to f2bf).
__device__ inline unsigned cvt_pk_bf16(float lo, float hi) {
  unsigned r;
  asm("v_cvt_pk_bf16_f32 %0, %1, %2" : "=v"(r) : "v"(lo), "v"(hi));
  return r;
}
#define MFMA_BF16(a, b, c) __builtin_amdgcn_mfma_f32_16x16x32_bf16((a), (b), (c), 0, 0, 0)

// Async global->LDS, 16B per lane. LDS dest is wave-uniform base + lane*16.
#define GLOAD_LDS16(gsrc, ldst)                                          \
  __builtin_amdgcn_global_load_lds(                                      \
      (const __attribute__((address_space(1))) void*)(gsrc),             \
      (__attribute__((address_space(3))) void*)(ldst), 16, 0, 0)

// ---------------------------------------------------------------------------
// Fused prep (round-8 exact).
// ---------------------------------------------------------------------------
__device__ inline void transpose_tile32(const float* __restrict__ W,
                                        short* __restrict__ Wt, int K, int N,
                                        int n0, int k0) {
  __shared__ float tile[32][33];
  const int r = threadIdx.x >> 3, c4 = (threadIdx.x & 7) * 4;
  float4 v = *(const float4*)(W + (size_t)(k0 + r) * N + n0 + c4);
  tile[r][c4 + 0] = v.x; tile[r][c4 + 1] = v.y;
  tile[r][c4 + 2] = v.z; tile[r][c4 + 3] = v.w;
  __syncthreads();
  s16x4 o;
  o[0] = f2bf(tile[c4 + 0][r]);
  o[1] = f2bf(tile[c4 + 1][r]);
  o[2] = f2bf(tile[c4 + 2][r]);
  o[3] = f2bf(tile[c4 + 3][r]);
  *(s16x4*)(Wt + (size_t)(n0 + r) * K + k0 + c4) = o;
}

__global__ __launch_bounds__(256) void prep_fused(
    const float* __restrict__ x, short* __restrict__ x16,
    const float* __restrict__ Wqkv, short* __restrict__ Wqt16,
    const float* __restrict__ Wout, short* __restrict__ Wot16,
    const float* __restrict__ ctr, const float* __restrict__ ls,
    const float* __restrict__ la, short* __restrict__ c16,
    float* __restrict__ csq, float* __restrict__ inv2, float* __restrict__ amp) {
  const int bx = blockIdx.x;
  if (bx < 4096) {
    int i = bx * 256 + threadIdx.x;
    float4 v = ((const float4*)x)[i];
    s16x4 o;
    o[0] = f2bf(v.x); o[1] = f2bf(v.y); o[2] = f2bf(v.z); o[3] = f2bf(v.w);
    ((s16x4*)x16)[i] = o;
  } else if (bx < 7168) {
    int idx = bx - 4096;
    transpose_tile32(Wqkv, Wqt16, 1024, 3072, (idx % 96) * 32, (idx / 96) * 32);
  } else if (bx < 8192) {
    int idx = bx - 7168;
    transpose_tile32(Wout, Wot16, 1024, 1024, (idx % 32) * 32, (idx / 32) * 32);
  } else {
    const int t = threadIdx.x;
    float sumsq = 0.f;
#pragma unroll
    for (int d = 0; d < 128; d += 4) {
      float4 v = *(const float4*)(ctr + (size_t)t * 128 + d);
      sumsq += v.x * v.x + v.y * v.y + v.z * v.z + v.w * v.w;
      s16x4 o;
      o[0] = f2bf(v.x); o[1] = f2bf(v.y); o[2] = f2bf(v.z); o[3] = f2bf(v.w);
      *(s16x4*)(c16 + (size_t)t * 128 + d) = o;
    }
    csq[t] = sumsq;
    float sc = __expf(ls[t]);
    float iv = 1.0f / (sc + 1e-6f);
    inv2[t] = -0.5f * iv * iv;
    amp[t] = __expf(la[t]);
  }
}

// ---------------------------------------------------------------------------
// bf16 MFMA GEMM with FUSED SPLAT epilogue (q/k thirds) — QKV.
// v-third: LDS-transpose coalesced vt16 write (R12-proven).
// ---------------------------------------------------------------------------
__global__ __launch_bounds__(256) void gemm_qkv(
    const short* __restrict__ A, const short* __restrict__ Wt,
    const float* __restrict__ bias,
    const short* __restrict__ c16, const float* __restrict__ csq,
    const float* __restrict__ inv2, const float* __restrict__ amp,
    short* __restrict__ qa16, short* __restrict__ kw16,
    short* __restrict__ vt16) {
  __shared__ union {
    struct { short As[128 * 64]; short Bs[128 * 64]; } s;  // 32 KB
    short tv[128 * 136];                                   // 34 KB
  } sm;
  const int tid = threadIdx.x;
  const int w = tid >> 6, l = tid & 63;
  const int lm = l & 15, lk = l >> 4;
  const int bn0 = blockIdx.x * 128;
  const int bm0 = blockIdx.y * 128;
  const int K = 1024;
  f32x4 acc[4][4];
#pragma unroll
  for (int mi = 0; mi < 4; mi++)
#pragma unroll
    for (int ni = 0; ni < 4; ni++) acc[mi][ni] = (f32x4){0.f, 0.f, 0.f, 0.f};

  const int srow = l >> 3;
  const int scol = (l & 7) * 8;
  const int mh = (w >> 1) * 64, nh = (w & 1) * 64;

  for (int k0 = 0; k0 < K; k0 += 64) {
#pragma unroll
    for (int q = 0; q < 4; q++) {
      const int chunk = w * 4 + q;
      const int row = chunk * 8 + srow;
      GLOAD_LDS16(A + (size_t)(bm0 + row) * K + k0 + scol, sm.s.As + chunk * 512);
      GLOAD_LDS16(Wt + (size_t)(bn0 + row) * K + k0 + scol, sm.s.Bs + chunk * 512);
    }
    __syncthreads();
#pragma unroll
    for (int kk = 0; kk < 2; kk++) {
      s16x8 af[4], bf[4];
#pragma unroll
      for (int i = 0; i < 4; i++) {
        af[i] = *(const s16x8*)(sm.s.As + (mh + i * 16 + lm) * 64 + kk * 32 + lk * 8);
        bf[i] = *(const s16x8*)(sm.s.Bs + (nh + i * 16 + lm) * 64 + kk * 32 + lk * 8);
      }
#pragma unroll
      for (int mi = 0; mi < 4; mi++)
#pragma unroll
        for (int ni = 0; ni < 4; ni++)
          acc[mi][ni] = MFMA_BF16(af[mi], bf[ni], acc[mi][ni]);
    }
    __syncthreads();
  }

  const int three = bn0 >> 10;            // 0=q, 1=k, 2=v (block-uniform)
  const int h = (bn0 >> 7) & 7;
  const int bb = bm0 >> 11;
  const int bh = bb * 8 + h;
  const int tt0 = bm0 & 2047;

  if (three < 2) {
    // ---- q/k: stage bf16 tile m-major, then fused splat (proven math). ----
#pragma unroll
    for (int ni = 0; ni < 4; ni++) {
      const int nl = nh + ni * 16 + lm;
      const float bv = bias[bn0 + nl];
#pragma unroll
      for (int mi = 0; mi < 4; mi++) {
#pragma unroll
        for (int r = 0; r < 4; r++) {
          const int ml = mh + mi * 16 + lk * 4 + r;
          sm.tv[ml * 136 + nl] = f2bf(acc[mi][ni][r] + bv);
        }
      }
    }
    __syncthreads();
    short* dst = three ? kw16 : qa16;
#pragma unroll
    for (int sub = 0; sub < 2; sub++) {
      const int iw = w * 32 + sub * 16;   // tile-row base of this subtile
      // A-frag from LDS: af[kk][e] = qk[t = tt0+iw+lm][dh = kk*32+lk*8+e]
      s16x8 af[4];
      float sq = 0.f;
#pragma unroll
      for (int kk = 0; kk < 4; kk++) {
        af[kk] = *(const s16x8*)(sm.tv + (iw + lm) * 136 + kk * 32 + lk * 8);
#pragma unroll
        for (int j = 0; j < 8; j++) {
          float f = bf2f(af[kk][j]);
          sq += f * f;
        }
      }
      sq += __shfl_xor(sq, 16);
      sq += __shfl_xor(sq, 32);
      f32x4 acc2[2];
      acc2[0] = (f32x4){0.f, 0.f, 0.f, 0.f};
      acc2[1] = (f32x4){0.f, 0.f, 0.f, 0.f};
#pragma unroll
      for (int kk = 0; kk < 4; kk++) {
        s16x8 b0 = *(const s16x8*)(c16 + (size_t)(h * 32 + lm) * 128 + kk * 32 + lk * 8);
        s16x8 b1 = *(const s16x8*)(c16 + (size_t)(h * 32 + 16 + lm) * 128 + kk * 32 + lk * 8);
        acc2[0] = MFMA_BF16(af[kk], b0, acc2[0]);
        acc2[1] = MFMA_BF16(af[kk], b1, acc2[1]);
      }
#pragma unroll
      for (int ni = 0; ni < 2; ni++) {
        const int n = ni * 16 + lm;
        const float cs = csq[h * 32 + n];
        const float iv2 = inv2[h * 32 + n];
        const float am = three ? 1.0f : amp[h * 32 + n];
#pragma unroll
        for (int r = 0; r < 4; r++) {
          float qs = __shfl(sq, lk * 4 + r);
          float d2 = fmaxf(qs + cs - 2.0f * acc2[ni][r], 0.0f);
          float wv = __expf(iv2 * d2) * am;
          const int m = tt0 + iw + lk * 4 + r;
          dst[((size_t)bh * 2048 + m) * 32 + n] = f2bf(wv);
        }
      }
    }
  } else {
    // ---- v: stage n-major in LDS, then coalesced transposed write-out. ----
#pragma unroll
    for (int ni = 0; ni < 4; ni++) {
      const int nl = nh + ni * 16 + lm;
      const float bv = bias[bn0 + nl];
#pragma unroll
      for (int mi = 0; mi < 4; mi++) {
        const int ml = mh + mi * 16 + lk * 4;
        s16x4 o;
        o[0] = f2bf(acc[mi][ni][0] + bv);
        o[1] = f2bf(acc[mi][ni][1] + bv);
        o[2] = f2bf(acc[mi][ni][2] + bv);
        o[3] = f2bf(acc[mi][ni][3] + bv);
        *(s16x4*)(sm.tv + nl * 136 + ml) = o;
      }
    }
    __syncthreads();
#pragma unroll
    for (int c = 0; c < 8; c++) {
      const int u = c * 256 + tid;
      const int n = u >> 4, ch = u & 15;
      s16x8 vv = *(const s16x8*)(sm.tv + n * 136 + ch * 8);
      *(s16x8*)(vt16 + ((size_t)(bh * 128 + n)) * 2048 + tt0 + ch * 8) = vv;
    }
  }
}

// ---------------------------------------------------------------------------
// Flash attention v11 (R12 exact): sigma-relabeled swapped-QK + LDS-staged V
// dbuf, full j-range, fused normalize -> direct aout16/lrow write.
// ---------------------------------------------------------------------------
__global__ __launch_bounds__(256) void attn_flash(
    const short* __restrict__ qa16, const short* __restrict__ kw16,
    const short* __restrict__ vt16, const float* __restrict__ temp,
    float* __restrict__ lrow, short* __restrict__ aout16) {
  __shared__ short Vs[2][8192];  // 2 x 16KB: [128 rows][8 slots of 16B]
  const int tid = threadIdx.x;
  const int w = tid >> 6, l = tid & 63;
  const int lm = l & 15, lk = l >> 4;
  const int it = blockIdx.x, h = blockIdx.y;
  const int b = blockIdx.z;
  const int bh = b * 8 + h;
  const int i0 = it * 64 + w * 16;
  const float invT = 1.0f / temp[0];
  const short* kwb = kw16 + (size_t)bh * 2048 * 32;
  const short* vtb = vt16 + (size_t)bh * 128 * 2048;
  s16x8 qfrag = *(const s16x8*)(qa16 + ((size_t)(bh * 2048 + i0 + lm)) * 32 + lk * 8);
  float lsum = 0.f;
  f32x4 acc[8];
#pragma unroll
  for (int d = 0; d < 8; d++) acc[d] = (f32x4){0.f, 0.f, 0.f, 0.f};

  const int sig0 = (lm >> 2) * 8 + (lm & 3);
  const int srow8 = l >> 3;
  const int scb = (l & 7) ^ srow8;
  const int rcb0 = (lk ^ (lm & 7)) * 8;
  const int rcb1 = ((lk + 4) ^ (lm & 7)) * 8;

#pragma unroll
  for (int q = 0; q < 4; q++) {
    const int chunk = w * 4 + q;
    GLOAD_LDS16(vtb + (size_t)(chunk * 8 + srow8) * 2048 + scb * 8,
                &Vs[0][chunk * 512]);
  }
  __syncthreads();

  int cur = 0;
  for (int jc = 0; jc < 2048; jc += 64) {
    if (jc + 64 < 2048) {
#pragma unroll
      for (int q = 0; q < 4; q++) {
        const int chunk = w * 4 + q;
        GLOAD_LDS16(vtb + (size_t)(chunk * 8 + srow8) * 2048 + (jc + 64) + scb * 8,
                    &Vs[cur ^ 1][chunk * 512]);
      }
    }
    s16x8 kb[4];
    kb[0] = *(const s16x8*)(kwb + (size_t)(jc + sig0) * 32 + lk * 8);
    kb[1] = *(const s16x8*)(kwb + (size_t)(jc + sig0 + 4) * 32 + lk * 8);
    kb[2] = *(const s16x8*)(kwb + (size_t)(jc + sig0 + 32) * 32 + lk * 8);
    kb[3] = *(const s16x8*)(kwb + (size_t)(jc + sig0 + 36) * 32 + lk * 8);
    f32x4 z = (f32x4){0.f, 0.f, 0.f, 0.f};
    f32x4 s[4];
#pragma unroll
    for (int c = 0; c < 4; c++) s[c] = MFMA_BF16(kb[c], qfrag, z);
    float p[4][4];
#pragma unroll
    for (int c = 0; c < 4; c++) {
      p[c][0] = __expf(s[c][0] * invT);
      p[c][1] = __expf(s[c][1] * invT);
      p[c][2] = __expf(s[c][2] * invT);
      p[c][3] = __expf(s[c][3] * invT);
      lsum += (p[c][0] + p[c][1]) + (p[c][2] + p[c][3]);
    }
    union { unsigned u[4]; s16x8 v; } t0, t1;
    t0.u[0] = cvt_pk_bf16(p[0][0], p[0][1]);
    t0.u[1] = cvt_pk_bf16(p[0][2], p[0][3]);
    t0.u[2] = cvt_pk_bf16(p[1][0], p[1][1]);
    t0.u[3] = cvt_pk_bf16(p[1][2], p[1][3]);
    t1.u[0] = cvt_pk_bf16(p[2][0], p[2][1]);
    t1.u[1] = cvt_pk_bf16(p[2][2], p[2][3]);
    t1.u[2] = cvt_pk_bf16(p[3][0], p[3][1]);
    t1.u[3] = cvt_pk_bf16(p[3][2], p[3][3]);
    s16x8 pf0 = t0.v, pf1 = t1.v;
    const short* vb = Vs[cur];
#pragma unroll
    for (int d = 0; d < 8; d++) {
      const short* vsrow = vb + (d * 16 + lm) * 64;
      s16x8 vb0 = *(const s16x8*)(vsrow + rcb0);
      s16x8 vb1 = *(const s16x8*)(vsrow + rcb1);
      acc[d] = MFMA_BF16(pf0, vb0, acc[d]);
      acc[d] = MFMA_BF16(pf1, vb1, acc[d]);
    }
    __syncthreads();
    cur ^= 1;
  }
  lsum += __shfl_xor(lsum, 16);
  lsum += __shfl_xor(lsum, 32);
  if (l < 16) lrow[bh * 2048 + i0 + l] = lsum;
  float invl[4];
#pragma unroll
  for (int r = 0; r < 4; r++) invl[r] = 1.0f / __shfl(lsum, lk * 4 + r);
  short* ob = aout16 + ((size_t)(b * 2048 + i0)) * 1024 + h * 128 + lm;
#pragma unroll
  for (int r = 0; r < 4; r++) {
    const int row = lk * 4 + r;
#pragma unroll
    for (int d = 0; d < 8; d++)
      ob[(size_t)row * 1024 + d * 16] = f2bf(acc[d][r] * invl[r]);
  }
}

// ---------------------------------------------------------------------------
// gemm_out: 128(M)x64(N) tiles, 512 blocks = 2 blocks/CU (R14 exact).
// ---------------------------------------------------------------------------
__global__ __launch_bounds__(256) void gemm_out(
    const short* __restrict__ aout16, const short* __restrict__ Wot16,
    const float* __restrict__ bout, float* __restrict__ out) {
  __shared__ short As[128 * 64];   // 16 KB
  __shared__ short Bs[64 * 64];    // 8 KB
  const int tid = threadIdx.x;
  const int w = tid >> 6, l = tid & 63;
  const int lm = l & 15, lk = l >> 4;
  const int idx = blockIdx.x;
  const int bn0 = (idx & 15) * 64;
  const int bm0 = (idx >> 4) * 128;
  const int K = 1024;
  f32x4 acc[4][2];
#pragma unroll
  for (int mi = 0; mi < 4; mi++)
#pragma unroll
    for (int ni = 0; ni < 2; ni++) acc[mi][ni] = (f32x4){0.f, 0.f, 0.f, 0.f};
  const int srow = l >> 3;
  const int scol = (l & 7) * 8;
  const int mh = (w >> 1) * 64, nh = (w & 1) * 32;
  for (int k0 = 0; k0 < K; k0 += 64) {
#pragma unroll
    for (int q = 0; q < 4; q++) {
      const int chunk = w * 4 + q;                 // 0..15: 128 A-rows
      GLOAD_LDS16(aout16 + (size_t)(bm0 + chunk * 8 + srow) * K + k0 + scol,
                  As + chunk * 512);
    }
#pragma unroll
    for (int q = 0; q < 2; q++) {
      const int chunk = w * 2 + q;                 // 0..7: 64 B-rows
      GLOAD_LDS16(Wot16 + (size_t)(bn0 + chunk * 8 + srow) * K + k0 + scol,
                  Bs + chunk * 512);
    }
    __syncthreads();
#pragma unroll
    for (int kk = 0; kk < 2; kk++) {
      s16x8 af[4], bf[2];
#pragma unroll
      for (int i = 0; i < 4; i++)
        af[i] = *(const s16x8*)(As + (mh + i * 16 + lm) * 64 + kk * 32 + lk * 8);
#pragma unroll
      for (int i = 0; i < 2; i++)
        bf[i] = *(const s16x8*)(Bs + (nh + i * 16 + lm) * 64 + kk * 32 + lk * 8);
#pragma unroll
      for (int mi = 0; mi < 4; mi++)
#pragma unroll
        for (int ni = 0; ni < 2; ni++)
          acc[mi][ni] = MFMA_BF16(af[mi], bf[ni], acc[mi][ni]);
    }
    __syncthreads();
  }
#pragma unroll
  for (int ni = 0; ni < 2; ni++) {
    const int n = bn0 + nh + ni * 16 + lm;
    const float bv = bout[n];
#pragma unroll
    for (int mi = 0; mi < 4; mi++) {
#pragma unroll
      for (int r = 0; r < 4; r++) {
        const int m = bm0 + mh + mi * 16 + lk * 4 + r;
        out[(size_t)m * 1024 + n] = acc[mi][ni][r] + bv;
      }
    }
  }
}

// ---------------------------------------------------------------------------
// attn_write: standalone, 16x32 tiles (R12 exact).
// ---------------------------------------------------------------------------
__global__ __launch_bounds__(256) void attn_write(
    const short* __restrict__ qa16, const short* __restrict__ kw16,
    const float* __restrict__ lrow, const float* __restrict__ temp,
    float* __restrict__ attn) {
  __shared__ float pl[8][16][33];
  const int tid = threadIdx.x;
  const int w = tid >> 6, l = tid & 63;
  const int lm = l & 15, lk = l >> 4;
  const int bx = blockIdx.x;
  const int i0 = (bx & 127) * 16;
  const int j0 = ((bx >> 7) & 63) * 32;
  const int b = bx >> 13;
  const float invT = 1.0f / temp[0];
#pragma unroll
  for (int hh = 0; hh < 2; hh++) {
    const int h = w * 2 + hh;
    const int bh = b * 8 + h;
    s16x8 qf = *(const s16x8*)(qa16 + ((size_t)(bh * 2048 + i0 + lm)) * 32 + lk * 8);
    s16x8 kf[2];
#pragma unroll
    for (int jh = 0; jh < 2; jh++)
      kf[jh] = *(const s16x8*)(kw16 + ((size_t)(bh * 2048 + j0 + jh * 16 + lm)) * 32 + lk * 8);
    float il[4];
#pragma unroll
    for (int r = 0; r < 4; r++)
      il[r] = 1.0f / lrow[bh * 2048 + i0 + lk * 4 + r];
    f32x4 z = (f32x4){0.f, 0.f, 0.f, 0.f};
#pragma unroll
    for (int jh = 0; jh < 2; jh++) {
      f32x4 s = MFMA_BF16(qf, kf[jh], z);
#pragma unroll
      for (int r = 0; r < 4; r++) {
        float p = __expf(s[r] * invT) * il[r];
        pl[h][lk * 4 + r][jh * 16 + lm] = p;
      }
    }
  }
  __syncthreads();
#pragma unroll
  for (int c = 0; c < 4; c++) {
    int u = c * 256 + tid;
    int i = u >> 6, rem = u & 63;
    int j = rem >> 1, h4 = (rem & 1) * 4;
    f32x4 v;
    v[0] = pl[h4][i][j];
    v[1] = pl[h4 + 1][i][j];
    v[2] = pl[h4 + 2][i][j];
    v[3] = pl[h4 + 3][i][j];
    f32x4* dst = (f32x4*)(attn + (((size_t)(b * 2048 + i0 + i)) * 2048 + j0 + j) * 8 + h4);
    __builtin_nontemporal_store(v, dst);
  }
}

// ---------------------------------------------------------------------------
extern "C" void kernel_launch(void* const* d_in, const int* in_sizes, int n_in,
                              void* d_out, int out_size, void* d_ws, size_t ws_size,
                              hipStream_t stream) {
  const float* x    = (const float*)d_in[0];
  const float* Wqkv = (const float*)d_in[1];
  const float* bqkv = (const float*)d_in[2];
  const float* Wout = (const float*)d_in[3];
  const float* bout = (const float*)d_in[4];
  const float* ctr  = (const float*)d_in[5];
  const float* ls   = (const float*)d_in[6];
  const float* la   = (const float*)d_in[7];
  const float* temp = (const float*)d_in[8];

  float* out = (float*)d_out;                 // (B,T,D)
  float* attn = out + 4194304;                // (B,T,T,H)

  short* ws16 = (short*)d_ws;
  short* vt16  = ws16;                        // 4,194,304 sh (B,H,Dh,T) bf16
  short* x16   = vt16 + 4194304;              // 4,194,304 sh
  short* Wqt16 = x16 + 4194304;               // 3,145,728 sh
  short* Wot16 = Wqt16 + 3145728;             // 1,048,576 sh
  short* qa16  = Wot16 + 1048576;             // 1,048,576 sh
  short* kw16  = qa16 + 1048576;              // 1,048,576 sh
  short* aout16 = kw16 + 1048576;             // 4,194,304 sh
  short* c16   = aout16 + 4194304;            // 32,768 sh
  float* lrow  = (float*)(c16 + 32768);       // 32,768 fl
  float* csq   = lrow + 32768;                // 256
  float* inv2  = csq + 256;
  float* amp   = inv2 + 256;

  prep_fused<<<8193, 256, 0, stream>>>(x, x16, Wqkv, Wqt16, Wout, Wot16,
                                       ctr, ls, la, c16, csq, inv2, amp);
  gemm_qkv<<<dim3(24, 32), 256, 0, stream>>>(
      x16, Wqt16, bqkv, c16, csq, inv2, amp, qa16, kw16, vt16);
  attn_flash<<<dim3(32, 8, 2), 256, 0, stream>>>(
      qa16, kw16, vt16, temp, lrow, aout16);
  gemm_out<<<512, 256, 0, stream>>>(aout16, Wot16, bout, out);
  attn_write<<<16384, 256, 0, stream>>>(qa16, kw16, lrow, temp, attn);
}

// Round 18
// 443.106 us; speedup vs baseline: 1.1772x; 1.0126x over previous
//
#include <hip/hip_runtime.h>
#include <math.h>

// Shapes: B=2, T=2048, D=1024, H=8, S=32, Dh=128, 3D=3072, B*T=4096
// POLISH R32 (resubmit — R17 bench was a GPUAcquisitionTimeout, no data).
// base = R16 (448.7us PASS; splat fused into QKV epilogue).
// Single change: flash v12 = v11 + K-window LDS staging. kb addresses don't
// depend on w -> all 4 waves loaded the same 8KB K-window from L2 each step
// (4x redundant) with the load->QK chain latency-exposed at 2 waves/SIMD.
// Fix mirrors R7's V staging: Ks[2][2048] double buffer, one gload_lds per
// wave per step, ds_read_b128 consumption with XOR swizzle
// swz(r) = ((r>>1)&3)^((r>>3)&3) (verified 2-way = free for all 4 kb rows;
// both-sides rule: pre-swizzled per-lane global source + swizzled read).
// Everything else R16-exact.

typedef __attribute__((ext_vector_type(8))) short s16x8;
typedef __attribute__((ext_vector_type(4))) short s16x4;
typedef __attribute__((ext_vector_type(4))) float f32x4;

__device__ inline short f2bf(float f) {
  union { float f; unsigned u; } v; v.f = f;
  unsigned r = v.u + 0x7FFFu + ((v.u >> 16) & 1u);
  return (short)(r >> 16);
}
__device__ inline float bf2f(short s) {
  union { unsigned u; float f; } v;
  v.u = ((unsigned)(unsigned short)s) << 16;
  return v.f;
}
// Packed f32x2 -> bf16x2, RNE (identical rounding to f2bf).
__device__ inline unsigned cvt_pk_bf16(float lo, float hi) {
  unsigned r;
  asm("v_cvt_pk_bf16_f32 %0, %1, %2" : "=v"(r) : "v"(lo), "v"(hi));
  return r;
}
__device__ inline int kswz(int r) { return ((r >> 1) & 3) ^ ((r >> 3) & 3); }
#define MFMA_BF16(a, b, c) __builtin_amdgcn_mfma_f32_16x16x32_bf16((a), (b), (c), 0, 0, 0)

// Async global->LDS, 16B per lane. LDS dest is wave-uniform base + lane*16.
#define GLOAD_LDS16(gsrc, ldst)                                          \
  __builtin_amdgcn_global_load_lds(                                      \
      (const __attribute__((address_space(1))) void*)(gsrc),             \
      (__attribute__((address_space(3))) void*)(ldst), 16, 0, 0)

// ---------------------------------------------------------------------------
// Fused prep (round-8 exact).
// ---------------------------------------------------------------------------
__device__ inline void transpose_tile32(const float* __restrict__ W,
                                        short* __restrict__ Wt, int K, int N,
                                        int n0, int k0) {
  __shared__ float tile[32][33];
  const int r = threadIdx.x >> 3, c4 = (threadIdx.x & 7) * 4;
  float4 v = *(const float4*)(W + (size_t)(k0 + r) * N + n0 + c4);
  tile[r][c4 + 0] = v.x; tile[r][c4 + 1] = v.y;
  tile[r][c4 + 2] = v.z; tile[r][c4 + 3] = v.w;
  __syncthreads();
  s16x4 o;
  o[0] = f2bf(tile[c4 + 0][r]);
  o[1] = f2bf(tile[c4 + 1][r]);
  o[2] = f2bf(tile[c4 + 2][r]);
  o[3] = f2bf(tile[c4 + 3][r]);
  *(s16x4*)(Wt + (size_t)(n0 + r) * K + k0 + c4) = o;
}

__global__ __launch_bounds__(256) void prep_fused(
    const float* __restrict__ x, short* __restrict__ x16,
    const float* __restrict__ Wqkv, short* __restrict__ Wqt16,
    const float* __restrict__ Wout, short* __restrict__ Wot16,
    const float* __restrict__ ctr, const float* __restrict__ ls,
    const float* __restrict__ la, short* __restrict__ c16,
    float* __restrict__ csq, float* __restrict__ inv2, float* __restrict__ amp) {
  const int bx = blockIdx.x;
  if (bx < 4096) {
    int i = bx * 256 + threadIdx.x;
    float4 v = ((const float4*)x)[i];
    s16x4 o;
    o[0] = f2bf(v.x); o[1] = f2bf(v.y); o[2] = f2bf(v.z); o[3] = f2bf(v.w);
    ((s16x4*)x16)[i] = o;
  } else if (bx < 7168) {
    int idx = bx - 4096;
    transpose_tile32(Wqkv, Wqt16, 1024, 3072, (idx % 96) * 32, (idx / 96) * 32);
  } else if (bx < 8192) {
    int idx = bx - 7168;
    transpose_tile32(Wout, Wot16, 1024, 1024, (idx % 32) * 32, (idx / 32) * 32);
  } else {
    const int t = threadIdx.x;
    float sumsq = 0.f;
#pragma unroll
    for (int d = 0; d < 128; d += 4) {
      float4 v = *(const float4*)(ctr + (size_t)t * 128 + d);
      sumsq += v.x * v.x + v.y * v.y + v.z * v.z + v.w * v.w;
      s16x4 o;
      o[0] = f2bf(v.x); o[1] = f2bf(v.y); o[2] = f2bf(v.z); o[3] = f2bf(v.w);
      *(s16x4*)(c16 + (size_t)t * 128 + d) = o;
    }
    csq[t] = sumsq;
    float sc = __expf(ls[t]);
    float iv = 1.0f / (sc + 1e-6f);
    inv2[t] = -0.5f * iv * iv;
    amp[t] = __expf(la[t]);
  }
}

// ---------------------------------------------------------------------------
// bf16 MFMA GEMM with FUSED SPLAT epilogue (q/k thirds) — QKV (R16 exact).
// ---------------------------------------------------------------------------
__global__ __launch_bounds__(256) void gemm_qkv(
    const short* __restrict__ A, const short* __restrict__ Wt,
    const float* __restrict__ bias,
    const short* __restrict__ c16, const float* __restrict__ csq,
    const float* __restrict__ inv2, const float* __restrict__ amp,
    short* __restrict__ qa16, short* __restrict__ kw16,
    short* __restrict__ vt16) {
  __shared__ union {
    struct { short As[128 * 64]; short Bs[128 * 64]; } s;  // 32 KB
    short tv[128 * 136];                                   // 34 KB
  } sm;
  const int tid = threadIdx.x;
  const int w = tid >> 6, l = tid & 63;
  const int lm = l & 15, lk = l >> 4;
  const int bn0 = blockIdx.x * 128;
  const int bm0 = blockIdx.y * 128;
  const int K = 1024;
  f32x4 acc[4][4];
#pragma unroll
  for (int mi = 0; mi < 4; mi++)
#pragma unroll
    for (int ni = 0; ni < 4; ni++) acc[mi][ni] = (f32x4){0.f, 0.f, 0.f, 0.f};

  const int srow = l >> 3;
  const int scol = (l & 7) * 8;
  const int mh = (w >> 1) * 64, nh = (w & 1) * 64;

  for (int k0 = 0; k0 < K; k0 += 64) {
#pragma unroll
    for (int q = 0; q < 4; q++) {
      const int chunk = w * 4 + q;
      const int row = chunk * 8 + srow;
      GLOAD_LDS16(A + (size_t)(bm0 + row) * K + k0 + scol, sm.s.As + chunk * 512);
      GLOAD_LDS16(Wt + (size_t)(bn0 + row) * K + k0 + scol, sm.s.Bs + chunk * 512);
    }
    __syncthreads();
#pragma unroll
    for (int kk = 0; kk < 2; kk++) {
      s16x8 af[4], bf[4];
#pragma unroll
      for (int i = 0; i < 4; i++) {
        af[i] = *(const s16x8*)(sm.s.As + (mh + i * 16 + lm) * 64 + kk * 32 + lk * 8);
        bf[i] = *(const s16x8*)(sm.s.Bs + (nh + i * 16 + lm) * 64 + kk * 32 + lk * 8);
      }
#pragma unroll
      for (int mi = 0; mi < 4; mi++)
#pragma unroll
        for (int ni = 0; ni < 4; ni++)
          acc[mi][ni] = MFMA_BF16(af[mi], bf[ni], acc[mi][ni]);
    }
    __syncthreads();
  }

  const int three = bn0 >> 10;            // 0=q, 1=k, 2=v (block-uniform)
  const int h = (bn0 >> 7) & 7;
  const int bb = bm0 >> 11;
  const int bh = bb * 8 + h;
  const int tt0 = bm0 & 2047;

  if (three < 2) {
    // ---- q/k: stage bf16 tile m-major, then fused splat (proven math). ----
#pragma unroll
    for (int ni = 0; ni < 4; ni++) {
      const int nl = nh + ni * 16 + lm;
      const float bv = bias[bn0 + nl];
#pragma unroll
      for (int mi = 0; mi < 4; mi++) {
#pragma unroll
        for (int r = 0; r < 4; r++) {
          const int ml = mh + mi * 16 + lk * 4 + r;
          sm.tv[ml * 136 + nl] = f2bf(acc[mi][ni][r] + bv);
        }
      }
    }
    __syncthreads();
    short* dst = three ? kw16 : qa16;
#pragma unroll
    for (int sub = 0; sub < 2; sub++) {
      const int iw = w * 32 + sub * 16;   // tile-row base of this subtile
      s16x8 af[4];
      float sq = 0.f;
#pragma unroll
      for (int kk = 0; kk < 4; kk++) {
        af[kk] = *(const s16x8*)(sm.tv + (iw + lm) * 136 + kk * 32 + lk * 8);
#pragma unroll
        for (int j = 0; j < 8; j++) {
          float f = bf2f(af[kk][j]);
          sq += f * f;
        }
      }
      sq += __shfl_xor(sq, 16);
      sq += __shfl_xor(sq, 32);
      f32x4 acc2[2];
      acc2[0] = (f32x4){0.f, 0.f, 0.f, 0.f};
      acc2[1] = (f32x4){0.f, 0.f, 0.f, 0.f};
#pragma unroll
      for (int kk = 0; kk < 4; kk++) {
        s16x8 b0 = *(const s16x8*)(c16 + (size_t)(h * 32 + lm) * 128 + kk * 32 + lk * 8);
        s16x8 b1 = *(const s16x8*)(c16 + (size_t)(h * 32 + 16 + lm) * 128 + kk * 32 + lk * 8);
        acc2[0] = MFMA_BF16(af[kk], b0, acc2[0]);
        acc2[1] = MFMA_BF16(af[kk], b1, acc2[1]);
      }
#pragma unroll
      for (int ni = 0; ni < 2; ni++) {
        const int n = ni * 16 + lm;
        const float cs = csq[h * 32 + n];
        const float iv2 = inv2[h * 32 + n];
        const float am = three ? 1.0f : amp[h * 32 + n];
#pragma unroll
        for (int r = 0; r < 4; r++) {
          float qs = __shfl(sq, lk * 4 + r);
          float d2 = fmaxf(qs + cs - 2.0f * acc2[ni][r], 0.0f);
          float wv = __expf(iv2 * d2) * am;
          const int m = tt0 + iw + lk * 4 + r;
          dst[((size_t)bh * 2048 + m) * 32 + n] = f2bf(wv);
        }
      }
    }
  } else {
    // ---- v: stage n-major in LDS, then coalesced transposed write-out. ----
#pragma unroll
    for (int ni = 0; ni < 4; ni++) {
      const int nl = nh + ni * 16 + lm;
      const float bv = bias[bn0 + nl];
#pragma unroll
      for (int mi = 0; mi < 4; mi++) {
        const int ml = mh + mi * 16 + lk * 4;
        s16x4 o;
        o[0] = f2bf(acc[mi][ni][0] + bv);
        o[1] = f2bf(acc[mi][ni][1] + bv);
        o[2] = f2bf(acc[mi][ni][2] + bv);
        o[3] = f2bf(acc[mi][ni][3] + bv);
        *(s16x4*)(sm.tv + nl * 136 + ml) = o;
      }
    }
    __syncthreads();
#pragma unroll
    for (int c = 0; c < 8; c++) {
      const int u = c * 256 + tid;
      const int n = u >> 4, ch = u & 15;
      s16x8 vv = *(const s16x8*)(sm.tv + n * 136 + ch * 8);
      *(s16x8*)(vt16 + ((size_t)(bh * 128 + n)) * 2048 + tt0 + ch * 8) = vv;
    }
  }
}

// ---------------------------------------------------------------------------
// Flash attention v12: v11 + K-window LDS double-buffer (swizzled).
// ---------------------------------------------------------------------------
__global__ __launch_bounds__(256) void attn_flash(
    const short* __restrict__ qa16, const short* __restrict__ kw16,
    const short* __restrict__ vt16, const float* __restrict__ temp,
    float* __restrict__ lrow, short* __restrict__ aout16) {
  __shared__ short Vs[2][8192];  // 2 x 16KB V: [128 rows][8 slots of 16B]
  __shared__ short Ks[2][2048];  // 2 x 4KB  K: [64 rows][4 slots of 16B]
  const int tid = threadIdx.x;
  const int w = tid >> 6, l = tid & 63;
  const int lm = l & 15, lk = l >> 4;
  const int it = blockIdx.x, h = blockIdx.y;
  const int b = blockIdx.z;
  const int bh = b * 8 + h;
  const int i0 = it * 64 + w * 16;
  const float invT = 1.0f / temp[0];
  const short* kwb = kw16 + (size_t)bh * 2048 * 32;
  const short* vtb = vt16 + (size_t)bh * 128 * 2048;
  s16x8 qfrag = *(const s16x8*)(qa16 + ((size_t)(bh * 2048 + i0 + lm)) * 32 + lk * 8);
  float lsum = 0.f;
  f32x4 acc[8];
#pragma unroll
  for (int d = 0; d < 8; d++) acc[d] = (f32x4){0.f, 0.f, 0.f, 0.f};

  const int sig0 = (lm >> 2) * 8 + (lm & 3);
  const int srow8 = l >> 3;
  const int scb = (l & 7) ^ srow8;
  const int rcb0 = (lk ^ (lm & 7)) * 8;
  const int rcb1 = ((lk + 4) ^ (lm & 7)) * 8;
  // K staging: wave w covers slots w*64 + l; slot s = (r, cb'), r=s>>2, cb'=s&3.
  // Slot holds K[jwin + r][(cb' ^ kswz(r))*8 ..], so source col = (l&3)^kswz(kr).
  const int kr = w * 16 + (l >> 2);
  const int kcol = (l & 3) ^ kswz(kr);
  // Loop-invariant swizzled read offsets for the 4 kb rows (shorts):
  const int r0 = sig0, r1 = sig0 + 4, r2 = sig0 + 32, r3 = sig0 + 36;
  const int ka0 = r0 * 32 + (lk ^ kswz(r0)) * 8;
  const int ka1 = r1 * 32 + (lk ^ kswz(r1)) * 8;
  const int ka2 = r2 * 32 + (lk ^ kswz(r2)) * 8;
  const int ka3 = r3 * 32 + (lk ^ kswz(r3)) * 8;

#pragma unroll
  for (int q = 0; q < 4; q++) {
    const int chunk = w * 4 + q;
    GLOAD_LDS16(vtb + (size_t)(chunk * 8 + srow8) * 2048 + scb * 8,
                &Vs[0][chunk * 512]);
  }
  GLOAD_LDS16(kwb + (size_t)kr * 32 + kcol * 8, &Ks[0][w * 512]);
  __syncthreads();

  int cur = 0;
  for (int jc = 0; jc < 2048; jc += 64) {
    if (jc + 64 < 2048) {
#pragma unroll
      for (int q = 0; q < 4; q++) {
        const int chunk = w * 4 + q;
        GLOAD_LDS16(vtb + (size_t)(chunk * 8 + srow8) * 2048 + (jc + 64) + scb * 8,
                    &Vs[cur ^ 1][chunk * 512]);
      }
      GLOAD_LDS16(kwb + (size_t)(jc + 64 + kr) * 32 + kcol * 8,
                  &Ks[cur ^ 1][w * 512]);
    }
    const short* kbb = Ks[cur];
    s16x8 kb[4];
    kb[0] = *(const s16x8*)(kbb + ka0);
    kb[1] = *(const s16x8*)(kbb + ka1);
    kb[2] = *(const s16x8*)(kbb + ka2);
    kb[3] = *(const s16x8*)(kbb + ka3);
    f32x4 z = (f32x4){0.f, 0.f, 0.f, 0.f};
    f32x4 s[4];
#pragma unroll
    for (int c = 0; c < 4; c++) s[c] = MFMA_BF16(kb[c], qfrag, z);
    float p[4][4];
#pragma unroll
    for (int c = 0; c < 4; c++) {
      p[c][0] = __expf(s[c][0] * invT);
      p[c][1] = __expf(s[c][1] * invT);
      p[c][2] = __expf(s[c][2] * invT);
      p[c][3] = __expf(s[c][3] * invT);
      lsum += (p[c][0] + p[c][1]) + (p[c][2] + p[c][3]);
    }
    union { unsigned u[4]; s16x8 v; } t0, t1;
    t0.u[0] = cvt_pk_bf16(p[0][0], p[0][1]);
    t0.u[1] = cvt_pk_bf16(p[0][2], p[0][3]);
    t0.u[2] = cvt_pk_bf16(p[1][0], p[1][1]);
    t0.u[3] = cvt_pk_bf16(p[1][2], p[1][3]);
    t1.u[0] = cvt_pk_bf16(p[2][0], p[2][1]);
    t1.u[1] = cvt_pk_bf16(p[2][2], p[2][3]);
    t1.u[2] = cvt_pk_bf16(p[3][0], p[3][1]);
    t1.u[3] = cvt_pk_bf16(p[3][2], p[3][3]);
    s16x8 pf0 = t0.v, pf1 = t1.v;
    const short* vb = Vs[cur];
#pragma unroll
    for (int d = 0; d < 8; d++) {
      const short* vsrow = vb + (d * 16 + lm) * 64;
      s16x8 vb0 = *(const s16x8*)(vsrow + rcb0);
      s16x8 vb1 = *(const s16x8*)(vsrow + rcb1);
      acc[d] = MFMA_BF16(pf0, vb0, acc[d]);
      acc[d] = MFMA_BF16(pf1, vb1, acc[d]);
    }
    __syncthreads();
    cur ^= 1;
  }
  lsum += __shfl_xor(lsum, 16);
  lsum += __shfl_xor(lsum, 32);
  if (l < 16) lrow[bh * 2048 + i0 + l] = lsum;
  float invl[4];
#pragma unroll
  for (int r = 0; r < 4; r++) invl[r] = 1.0f / __shfl(lsum, lk * 4 + r);
  short* ob = aout16 + ((size_t)(b * 2048 + i0)) * 1024 + h * 128 + lm;
#pragma unroll
  for (int r = 0; r < 4; r++) {
    const int row = lk * 4 + r;
#pragma unroll
    for (int d = 0; d < 8; d++)
      ob[(size_t)row * 1024 + d * 16] = f2bf(acc[d][r] * invl[r]);
  }
}

// ---------------------------------------------------------------------------
// gemm_out: 128(M)x64(N) tiles, 512 blocks = 2 blocks/CU (R14 exact).
// ---------------------------------------------------------------------------
__global__ __launch_bounds__(256) void gemm_out(
    const short* __restrict__ aout16, const short* __restrict__ Wot16,
    const float* __restrict__ bout, float* __restrict__ out) {
  __shared__ short As[128 * 64];   // 16 KB
  __shared__ short Bs[64 * 64];    // 8 KB
  const int tid = threadIdx.x;
  const int w = tid >> 6, l = tid & 63;
  const int lm = l & 15, lk = l >> 4;
  const int idx = blockIdx.x;
  const int bn0 = (idx & 15) * 64;
  const int bm0 = (idx >> 4) * 128;
  const int K = 1024;
  f32x4 acc[4][2];
#pragma unroll
  for (int mi = 0; mi < 4; mi++)
#pragma unroll
    for (int ni = 0; ni < 2; ni++) acc[mi][ni] = (f32x4){0.f, 0.f, 0.f, 0.f};
  const int srow = l >> 3;
  const int scol = (l & 7) * 8;
  const int mh = (w >> 1) * 64, nh = (w & 1) * 32;
  for (int k0 = 0; k0 < K; k0 += 64) {
#pragma unroll
    for (int q = 0; q < 4; q++) {
      const int chunk = w * 4 + q;                 // 0..15: 128 A-rows
      GLOAD_LDS16(aout16 + (size_t)(bm0 + chunk * 8 + srow) * K + k0 + scol,
                  As + chunk * 512);
    }
#pragma unroll
    for (int q = 0; q < 2; q++) {
      const int chunk = w * 2 + q;                 // 0..7: 64 B-rows
      GLOAD_LDS16(Wot16 + (size_t)(bn0 + chunk * 8 + srow) * K + k0 + scol,
                  Bs + chunk * 512);
    }
    __syncthreads();
#pragma unroll
    for (int kk = 0; kk < 2; kk++) {
      s16x8 af[4], bf[2];
#pragma unroll
      for (int i = 0; i < 4; i++)
        af[i] = *(const s16x8*)(As + (mh + i * 16 + lm) * 64 + kk * 32 + lk * 8);
#pragma unroll
      for (int i = 0; i < 2; i++)
        bf[i] = *(const s16x8*)(Bs + (nh + i * 16 + lm) * 64 + kk * 32 + lk * 8);
#pragma unroll
      for (int mi = 0; mi < 4; mi++)
#pragma unroll
        for (int ni = 0; ni < 2; ni++)
          acc[mi][ni] = MFMA_BF16(af[mi], bf[ni], acc[mi][ni]);
    }
    __syncthreads();
  }
#pragma unroll
  for (int ni = 0; ni < 2; ni++) {
    const int n = bn0 + nh + ni * 16 + lm;
    const float bv = bout[n];
#pragma unroll
    for (int mi = 0; mi < 4; mi++) {
#pragma unroll
      for (int r = 0; r < 4; r++) {
        const int m = bm0 + mh + mi * 16 + lk * 4 + r;
        out[(size_t)m * 1024 + n] = acc[mi][ni][r] + bv;
      }
    }
  }
}

// ---------------------------------------------------------------------------
// attn_write: standalone, 16x32 tiles (R12 exact).
// ---------------------------------------------------------------------------
__global__ __launch_bounds__(256) void attn_write(
    const short* __restrict__ qa16, const short* __restrict__ kw16,
    const float* __restrict__ lrow, const float* __restrict__ temp,
    float* __restrict__ attn) {
  __shared__ float pl[8][16][33];
  const int tid = threadIdx.x;
  const int w = tid >> 6, l = tid & 63;
  const int lm = l & 15, lk = l >> 4;
  const int bx = blockIdx.x;
  const int i0 = (bx & 127) * 16;
  const int j0 = ((bx >> 7) & 63) * 32;
  const int b = bx >> 13;
  const float invT = 1.0f / temp[0];
#pragma unroll
  for (int hh = 0; hh < 2; hh++) {
    const int h = w * 2 + hh;
    const int bh = b * 8 + h;
    s16x8 qf = *(const s16x8*)(qa16 + ((size_t)(bh * 2048 + i0 + lm)) * 32 + lk * 8);
    s16x8 kf[2];
#pragma unroll
    for (int jh = 0; jh < 2; jh++)
      kf[jh] = *(const s16x8*)(kw16 + ((size_t)(bh * 2048 + j0 + jh * 16 + lm)) * 32 + lk * 8);
    float il[4];
#pragma unroll
    for (int r = 0; r < 4; r++)
      il[r] = 1.0f / lrow[bh * 2048 + i0 + lk * 4 + r];
    f32x4 z = (f32x4){0.f, 0.f, 0.f, 0.f};
#pragma unroll
    for (int jh = 0; jh < 2; jh++) {
      f32x4 s = MFMA_BF16(qf, kf[jh], z);
#pragma unroll
      for (int r = 0; r < 4; r++) {
        float p = __expf(s[r] * invT) * il[r];
        pl[h][lk * 4 + r][jh * 16 + lm] = p;
      }
    }
  }
  __syncthreads();
#pragma unroll
  for (int c = 0; c < 4; c++) {
    int u = c * 256 + tid;
    int i = u >> 6, rem = u & 63;
    int j = rem >> 1, h4 = (rem & 1) * 4;
    f32x4 v;
    v[0] = pl[h4][i][j];
    v[1] = pl[h4 + 1][i][j];
    v[2] = pl[h4 + 2][i][j];
    v[3] = pl[h4 + 3][i][j];
    f32x4* dst = (f32x4*)(attn + (((size_t)(b * 2048 + i0 + i)) * 2048 + j0 + j) * 8 + h4);
    __builtin_nontemporal_store(v, dst);
  }
}

// ---------------------------------------------------------------------------
extern "C" void kernel_launch(void* const* d_in, const int* in_sizes, int n_in,
                              void* d_out, int out_size, void* d_ws, size_t ws_size,
                              hipStream_t stream) {
  const float* x    = (const float*)d_in[0];
  const float* Wqkv = (const float*)d_in[1];
  const float* bqkv = (const float*)d_in[2];
  const float* Wout = (const float*)d_in[3];
  const float* bout = (const float*)d_in[4];
  const float* ctr  = (const float*)d_in[5];
  const float* ls   = (const float*)d_in[6];
  const float* la   = (const float*)d_in[7];
  const float* temp = (const float*)d_in[8];

  float* out = (float*)d_out;                 // (B,T,D)
  float* attn = out + 4194304;                // (B,T,T,H)

  short* ws16 = (short*)d_ws;
  short* vt16  = ws16;                        // 4,194,304 sh (B,H,Dh,T) bf16
  short* x16   = vt16 + 4194304;              // 4,194,304 sh
  short* Wqt16 = x16 + 4194304;               // 3,145,728 sh
  short* Wot16 = Wqt16 + 3145728;             // 1,048,576 sh
  short* qa16  = Wot16 + 1048576;             // 1,048,576 sh
  short* kw16  = qa16 + 1048576;              // 1,048,576 sh
  short* aout16 = kw16 + 1048576;             // 4,194,304 sh
  short* c16   = aout16 + 4194304;            // 32,768 sh
  float* lrow  = (float*)(c16 + 32768);       // 32,768 fl
  float* csq   = lrow + 32768;                // 256
  float* inv2  = csq + 256;
  float* amp   = inv2 + 256;

  prep_fused<<<8193, 256, 0, stream>>>(x, x16, Wqkv, Wqt16, Wout, Wot16,
                                       ctr, ls, la, c16, csq, inv2, amp);
  gemm_qkv<<<dim3(24, 32), 256, 0, stream>>>(
      x16, Wqt16, bqkv, c16, csq, inv2, amp, qa16, kw16, vt16);
  attn_flash<<<dim3(32, 8, 2), 256, 0, stream>>>(
      qa16, kw16, vt16, temp, lrow, aout16);
  gemm_out<<<512, 256, 0, stream>>>(aout16, Wot16, bout, out);
  attn_write<<<16384, 256, 0, stream>>>(qa16, kw16, lrow, temp, attn);
}